// Round 4
// baseline (2076.450 us; speedup 1.0000x reference)
//
#include <hip/hip_runtime.h>
#include <math.h>

// ---------------------------------------------------------------------------
// CausalSelfAttention fused pipeline, MI355X gfx950.  Round 4.
// Settled: inputs f32 (round-1 NaN reading them as bf16), OUTPUT f32 (harness
// doc: d_out is the reference's output dtype; the "(bf16,...)" label in the
// test is hardcoded). Rounds 2/3 wrote bf16 into the f32 out buffer ->
// bit-identical 0.889 garbage. Only change this round: proj GEMM writes f32.
// Workspace: q(=y) 8MB | k 8MB | v 8MB | gate 256KB = 24.25MB.
// ---------------------------------------------------------------------------

#define B_    2
#define T_    2048
#define DIM_  1024
#define H_    16
#define HD_   64
#define NROW  (B_ * T_)          // 4096
#define EPS_  1.1920929e-07f
#define SCALE_ 0.1f

typedef unsigned short u16;
typedef unsigned int   u32;
typedef __bf16 bf16x8 __attribute__((ext_vector_type(8)));
typedef float  f32x4  __attribute__((ext_vector_type(4)));

__device__ __forceinline__ float b2f(u16 u) {
  return __uint_as_float(((u32)u) << 16);
}
__device__ __forceinline__ u16 f2b(float f) {
  u32 u = __float_as_uint(f);
  u += 0x7fffu + ((u >> 16) & 1u);       // round-to-nearest-even
  return (u16)(u >> 16);
}

__device__ __forceinline__ u32 pk(float a, float b) {
  return (u32)f2b(a) | ((u32)f2b(b) << 16);
}

// ---------------------------------------------------------------------------
// GEMM: C[row, n] = sum_k A[row, k] * W[n, k]  (= A @ W^T), bf16 MFMA core.
// A: NROW x DIM (f32 or bf16 per ABF16), W: DIM x DIM (f32).
// Block tile 64x64, 4 waves, each wave 32x32 via 2x2 MFMA 16x16x32 accs.
// Staging in MFMA fragment order (slot l: row l&15, k (l>>4)*8..+7) so the
// consumer LDS->frag read is one conflict-free ds_read_b128 at lane*16.
// MODE 0: rmsnorm+rope -> bf16 C.  MODE 1: lamb-blend with v1 -> bf16 C.
// MODE 2: plain -> f32 C (d_out).
// ---------------------------------------------------------------------------
template <int MODE, bool ABF16>
__global__ __launch_bounds__(256) void gemm_ep(
    const void* __restrict__ Av, const float* __restrict__ W, void* __restrict__ Cv,
    const float* __restrict__ v1, const float* __restrict__ lambp) {
  __shared__ __attribute__((aligned(16))) unsigned char smem[17664];
  const int tid  = threadIdx.x;
  const int w    = tid >> 6;
  const int lane = tid & 63;
  const int m0   = blockIdx.x << 6;
  const int n0   = blockIdx.y << 6;

  f32x4 acc00 = {0.f, 0.f, 0.f, 0.f};
  f32x4 acc01 = acc00, acc10 = acc00, acc11 = acc00;

  // staging: wave w fills A-subtile w and W-subtile w each 32-k chunk
  const int srow = lane & 15;          // row within 16-row subtile
  const int skb  = (lane >> 4) << 3;   // k base within 32-k chunk
  const float* gaf = ABF16 ? nullptr
      : (const float*)Av + (size_t)(m0 + (w << 4) + srow) * DIM_ + skb;
  const u16* gab = ABF16
      ? (const u16*)Av + (size_t)(m0 + (w << 4) + srow) * DIM_ + skb : nullptr;
  const float* gw = W + (size_t)(n0 + (w << 4) + srow) * DIM_ + skb;
  uint4* ldsA = (uint4*)(smem + (w << 10) + (lane << 4));
  uint4* ldsW = (uint4*)(smem + 4096 + (w << 10) + (lane << 4));

  const int mh = (w & 1) << 1;   // this wave's m subtile base (0 or 2)
  const int nh = (w >> 1) << 1;  // this wave's n subtile base (0 or 2)
  const unsigned char* pa0 = smem + ((mh + 0) << 10) + (lane << 4);
  const unsigned char* pa1 = smem + ((mh + 1) << 10) + (lane << 4);
  const unsigned char* pb0 = smem + 4096 + ((nh + 0) << 10) + (lane << 4);
  const unsigned char* pb1 = smem + 4096 + ((nh + 1) << 10) + (lane << 4);

  for (int kc = 0; kc < DIM_; kc += 32) {
    uint4 pa, pw;
    if constexpr (ABF16) {
      pa = *(const uint4*)gab;
      gab += 32;
    } else {
      const float4 lo = *(const float4*)gaf;
      const float4 hi = *(const float4*)(gaf + 4);
      gaf += 32;
      pa.x = pk(lo.x, lo.y); pa.y = pk(lo.z, lo.w);
      pa.z = pk(hi.x, hi.y); pa.w = pk(hi.z, hi.w);
    }
    {
      const float4 lo = *(const float4*)gw;
      const float4 hi = *(const float4*)(gw + 4);
      gw += 32;
      pw.x = pk(lo.x, lo.y); pw.y = pk(lo.z, lo.w);
      pw.z = pk(hi.x, hi.y); pw.w = pk(hi.z, hi.w);
    }
    __syncthreads();             // prior tile's ds_reads complete
    *ldsA = pa;
    *ldsW = pw;
    __syncthreads();             // staged tile visible
    const bf16x8 a0 = *(const bf16x8*)pa0;
    const bf16x8 a1 = *(const bf16x8*)pa1;
    const bf16x8 b0 = *(const bf16x8*)pb0;
    const bf16x8 b1 = *(const bf16x8*)pb1;
    acc00 = __builtin_amdgcn_mfma_f32_16x16x32_bf16(a0, b0, acc00, 0, 0, 0);
    acc01 = __builtin_amdgcn_mfma_f32_16x16x32_bf16(a0, b1, acc01, 0, 0, 0);
    acc10 = __builtin_amdgcn_mfma_f32_16x16x32_bf16(a1, b0, acc10, 0, 0, 0);
    acc11 = __builtin_amdgcn_mfma_f32_16x16x32_bf16(a1, b1, acc11, 0, 0, 0);
  }
  __syncthreads();               // last tile's ds_reads done before Ct reuse

  // spill accumulators to LDS C tile (64 x 64, row stride 65 floats)
  float* Ct = (float*)smem;
  {
    const int rq = (lane >> 4) << 2;   // C/D: row = (lane>>4)*4 + reg
    const int cq = lane & 15;          //      col = lane & 15
#pragma unroll
    for (int r = 0; r < 4; ++r) {
      Ct[(mh * 16 + rq + r) * 65 + nh * 16 + cq]            = acc00[r];
      Ct[(mh * 16 + rq + r) * 65 + nh * 16 + 16 + cq]       = acc01[r];
      Ct[((mh + 1) * 16 + rq + r) * 65 + nh * 16 + cq]      = acc10[r];
      Ct[((mh + 1) * 16 + rq + r) * 65 + nh * 16 + 16 + cq] = acc11[r];
    }
  }
  __syncthreads();

  // epilogue: 4 threads per row, 16 cols each
  const int r   = tid >> 2;
  const int c0  = (tid & 3) << 4;
  const int row = m0 + r;
  const float* cr = Ct + r * 65;

  if (MODE == 0) {
    u16* crow = (u16*)Cv + (size_t)row * DIM_ + n0;
    // rmsnorm over the 64-wide head (n-block == one head), then rope
    float* ssq = (float*)(smem + 16640);
    float ss = 0.f;
#pragma unroll
    for (int i = 0; i < 16; ++i) { const float vv = cr[c0 + i]; ss += vv * vv; }
    ssq[tid] = ss;
    __syncthreads();
    const float tot = ssq[r << 2] + ssq[(r << 2) + 1] + ssq[(r << 2) + 2] + ssq[(r << 2) + 3];
    const float scale = rsqrtf(tot * (1.0f / 64.0f) + EPS_);
    const float tpos = (float)(row & (T_ - 1));
#pragma unroll
    for (int i = 0; i < 16; ++i) {
      const int c = c0 + i;
      const int fi = c & 31;
      const float vlo = cr[fi] * scale;        // x1[fi]
      const float vhi = cr[fi + 32] * scale;   // x2[fi]
      const float fr = tpos * powf(10000.0f, -(float)fi * (1.0f / 32.0f));
      float sn, cs;
      sincosf(fr, &sn, &cs);
      const float o = (c < 32) ? (vlo * cs + vhi * sn) : (vhi * cs - vlo * sn);
      crow[c] = f2b(o);
    }
  } else if (MODE == 1) {
    u16* crow = (u16*)Cv + (size_t)row * DIM_ + n0;
    const float lam = lambp[0];
    const float* v1row = v1 + (size_t)row * DIM_ + n0;
#pragma unroll
    for (int i = 0; i < 16; ++i) {
      const int c = c0 + i;
      crow[c] = f2b((1.f - lam) * cr[c] + lam * v1row[c]);
    }
  } else {
    float* crow = (float*)Cv + (size_t)row * DIM_ + n0;   // f32 final output
#pragma unroll
    for (int i = 0; i < 16; ++i) crow[c0 + i] = cr[c0 + i];
  }
}

// ---------------------------------------------------------------------------
// gate[n, h] = sigmoid( sum_{j<12} x[n, j] * Wg[h, j] )   (all f32)
// ---------------------------------------------------------------------------
__global__ __launch_bounds__(256) void gate_kernel(
    const float* __restrict__ x, const float* __restrict__ Wg,
    float* __restrict__ gate) {
  const int id = blockIdx.x * 256 + threadIdx.x;   // 0 .. NROW*H-1
  const int n = id >> 4, h = id & 15;
  const float* xr = x + (size_t)n * DIM_;
  const float* wr = Wg + h * 12;
  float s = 0.f;
#pragma unroll
  for (int j = 0; j < 12; ++j) s += xr[j] * wr[j];
  gate[id] = 1.f / (1.f + __expf(-s));
}

// ---------------------------------------------------------------------------
// Attention: 1 wave per query row, online softmax over 64-key chunks.
// phase 1: lane = key pos (vectorized k-row loads, q in LDS)
// phase 2: lane = head dim (coalesced v loads), p broadcast via LDS.
// Chunk count uniform across the block so __syncthreads is legal.
// y aliases q safely: each (b,h,t) q stripe is read only by its own wave,
// before that wave's single y write.
// ---------------------------------------------------------------------------
__global__ __launch_bounds__(256) void attn_kernel(
    const u16* __restrict__ q, const u16* __restrict__ k, const u16* __restrict__ v,
    const float* __restrict__ gate, u16* __restrict__ y) {
  __shared__ float q_s[4][64];
  __shared__ float p_s[4][64];
  const int w    = threadIdx.x >> 6;
  const int lane = threadIdx.x & 63;
  const int qg   = blockIdx.x & 511;
  const int bh   = blockIdx.x >> 9;
  const int b    = bh >> 4;
  const int h    = bh & 15;
  const int t    = (qg << 2) + w;

  const size_t rowoff = (size_t)(b * T_ + t) * DIM_ + h * HD_;
  q_s[w][lane] = b2f(q[rowoff + lane]);
  __syncthreads();

  const u16* kbase = k + (size_t)(b * T_) * DIM_ + h * HD_;
  const u16* vcol  = v + (size_t)(b * T_) * DIM_ + h * HD_ + lane;

  float m = -1e30f, l = 0.f, acc = 0.f;
  const int nch = ((t | 3) >> 6) + 1;   // uniform across the block

  for (int c = 0; c < nch; ++c) {
    const int pos = (c << 6) + lane;
    float s = -1e30f;
    if (pos <= t) {
      const uint4* k4 = (const uint4*)(kbase + (size_t)pos * DIM_);
      float dot = 0.f;
#pragma unroll
      for (int cc = 0; cc < 8; ++cc) {
        const uint4 kk = k4[cc];
        const float* qs = &q_s[w][cc << 3];
        dot += b2f((u16)(kk.x & 0xffff)) * qs[0] + b2f((u16)(kk.x >> 16)) * qs[1]
             + b2f((u16)(kk.y & 0xffff)) * qs[2] + b2f((u16)(kk.y >> 16)) * qs[3]
             + b2f((u16)(kk.z & 0xffff)) * qs[4] + b2f((u16)(kk.z >> 16)) * qs[5]
             + b2f((u16)(kk.w & 0xffff)) * qs[6] + b2f((u16)(kk.w >> 16)) * qs[7];
      }
      s = dot * SCALE_;
    }
    float cm = s;
#pragma unroll
    for (int off = 32; off > 0; off >>= 1) cm = fmaxf(cm, __shfl_xor(cm, off, 64));
    const float mn = fmaxf(m, cm);
    const float alpha = __expf(m - mn);          // first chunk: exp(-huge) = 0
    const float p = (pos <= t) ? __expf(s - mn) : 0.f;
    float psum = p;
#pragma unroll
    for (int off = 32; off > 0; off >>= 1) psum += __shfl_xor(psum, off, 64);
    l = l * alpha + psum;
    m = mn;
    __syncthreads();             // prior-chunk p_s reads done before overwrite
    p_s[w][lane] = p;
    __syncthreads();             // p_s visible
    acc *= alpha;
    const int valid = min(64, t + 1 - (c << 6));
    const u16* vp = vcol + ((size_t)(c << 6)) * DIM_;
    for (int j = 0; j < valid; ++j) {
      acc += p_s[w][j] * b2f(vp[(size_t)j * DIM_]);
    }
  }
  const float g = gate[(size_t)(b * T_ + t) * H_ + h];
  y[rowoff + lane] = f2b(acc / l * g);
}

// ---------------------------------------------------------------------------
extern "C" void kernel_launch(void* const* d_in, const int* in_sizes, int n_in,
                              void* d_out, int out_size, void* d_ws, size_t ws_size,
                              hipStream_t stream) {
  const float* x    = (const float*)d_in[0];
  const float* v1   = (const float*)d_in[1];
  const float* Wq   = (const float*)d_in[2];
  const float* Wk   = (const float*)d_in[3];
  const float* Wv   = (const float*)d_in[4];
  const float* Wp   = (const float*)d_in[5];
  const float* Wg   = (const float*)d_in[6];
  const float* lamb = (const float*)d_in[7];

  const size_t NX = (size_t)NROW * DIM_;   // 4M elements

  u16* q = (u16*)d_ws;                     // also y (in-place)
  u16* k = q + NX;
  u16* v = k + NX;
  float* gate = (float*)(v + NX);          // total ws: 24.25 MB

  const dim3 bb(256);
  const dim3 gg(NROW / 64, DIM_ / 64);

  gemm_ep<0, false><<<gg, bb, 0, stream>>>(x, Wq, q, nullptr, nullptr);
  gemm_ep<0, false><<<gg, bb, 0, stream>>>(x, Wk, k, nullptr, nullptr);
  gemm_ep<1, false><<<gg, bb, 0, stream>>>(x, Wv, v, v1, lamb);
  gate_kernel<<<dim3(NROW * H_ / 256), bb, 0, stream>>>(x, Wg, gate);
  attn_kernel<<<dim3(B_ * H_ * (T_ / 4)), bb, 0, stream>>>(q, k, v, gate, q);
  gemm_ep<2, true><<<gg, bb, 0, stream>>>(q, Wp, (float*)d_out, nullptr, nullptr);
}

// Round 5
// 489.804 us; speedup vs baseline: 4.2394x; 4.2394x over previous
//
#include <hip/hip_runtime.h>
#include <math.h>

// ---------------------------------------------------------------------------
// CausalSelfAttention fused pipeline, MI355X gfx950.  Round 5.
// Round-4 passed (absmax 3.9e-3); attn_kernel was 1825/2076 us, MfmaUtil=0.
// This round: MFMA flash attention (block = (b,h,64-q-tile), 4 waves, K/V
// 64-key LDS tiles, online softmax in C-layout regs, P via per-wave LDS
// transpose, PV MFMA). GEMMs/gate unchanged.
// Workspace: q(=y) 8MB | k 8MB | v 8MB | gate 256KB = 24.25MB.
// ---------------------------------------------------------------------------

#define B_    2
#define T_    2048
#define DIM_  1024
#define H_    16
#define HD_   64
#define NROW  (B_ * T_)          // 4096
#define EPS_  1.1920929e-07f
#define SCALE_ 0.1f

typedef unsigned short u16;
typedef unsigned int   u32;
typedef __bf16 bf16x8 __attribute__((ext_vector_type(8)));
typedef float  f32x4  __attribute__((ext_vector_type(4)));

__device__ __forceinline__ float b2f(u16 u) {
  return __uint_as_float(((u32)u) << 16);
}
__device__ __forceinline__ u16 f2b(float f) {
  u32 u = __float_as_uint(f);
  u += 0x7fffu + ((u >> 16) & 1u);       // round-to-nearest-even
  return (u16)(u >> 16);
}
__device__ __forceinline__ u32 pk(float a, float b) {
  return (u32)f2b(a) | ((u32)f2b(b) << 16);
}
#define MFMA16(a, b, c) __builtin_amdgcn_mfma_f32_16x16x32_bf16((a), (b), (c), 0, 0, 0)

// ---------------------------------------------------------------------------
// GEMM: C[row, n] = sum_k A[row, k] * W[n, k]  (= A @ W^T), bf16 MFMA core.
// (unchanged from round 4 — passing baseline)
// ---------------------------------------------------------------------------
template <int MODE, bool ABF16>
__global__ __launch_bounds__(256) void gemm_ep(
    const void* __restrict__ Av, const float* __restrict__ W, void* __restrict__ Cv,
    const float* __restrict__ v1, const float* __restrict__ lambp) {
  __shared__ __attribute__((aligned(16))) unsigned char smem[17664];
  const int tid  = threadIdx.x;
  const int w    = tid >> 6;
  const int lane = tid & 63;
  const int m0   = blockIdx.x << 6;
  const int n0   = blockIdx.y << 6;

  f32x4 acc00 = {0.f, 0.f, 0.f, 0.f};
  f32x4 acc01 = acc00, acc10 = acc00, acc11 = acc00;

  const int srow = lane & 15;
  const int skb  = (lane >> 4) << 3;
  const float* gaf = ABF16 ? nullptr
      : (const float*)Av + (size_t)(m0 + (w << 4) + srow) * DIM_ + skb;
  const u16* gab = ABF16
      ? (const u16*)Av + (size_t)(m0 + (w << 4) + srow) * DIM_ + skb : nullptr;
  const float* gw = W + (size_t)(n0 + (w << 4) + srow) * DIM_ + skb;
  uint4* ldsA = (uint4*)(smem + (w << 10) + (lane << 4));
  uint4* ldsW = (uint4*)(smem + 4096 + (w << 10) + (lane << 4));

  const int mh = (w & 1) << 1;
  const int nh = (w >> 1) << 1;
  const unsigned char* pa0 = smem + ((mh + 0) << 10) + (lane << 4);
  const unsigned char* pa1 = smem + ((mh + 1) << 10) + (lane << 4);
  const unsigned char* pb0 = smem + 4096 + ((nh + 0) << 10) + (lane << 4);
  const unsigned char* pb1 = smem + 4096 + ((nh + 1) << 10) + (lane << 4);

  for (int kc = 0; kc < DIM_; kc += 32) {
    uint4 pa, pw;
    if constexpr (ABF16) {
      pa = *(const uint4*)gab;
      gab += 32;
    } else {
      const float4 lo = *(const float4*)gaf;
      const float4 hi = *(const float4*)(gaf + 4);
      gaf += 32;
      pa.x = pk(lo.x, lo.y); pa.y = pk(lo.z, lo.w);
      pa.z = pk(hi.x, hi.y); pa.w = pk(hi.z, hi.w);
    }
    {
      const float4 lo = *(const float4*)gw;
      const float4 hi = *(const float4*)(gw + 4);
      gw += 32;
      pw.x = pk(lo.x, lo.y); pw.y = pk(lo.z, lo.w);
      pw.z = pk(hi.x, hi.y); pw.w = pk(hi.z, hi.w);
    }
    __syncthreads();
    *ldsA = pa;
    *ldsW = pw;
    __syncthreads();
    const bf16x8 a0 = *(const bf16x8*)pa0;
    const bf16x8 a1 = *(const bf16x8*)pa1;
    const bf16x8 b0 = *(const bf16x8*)pb0;
    const bf16x8 b1 = *(const bf16x8*)pb1;
    acc00 = MFMA16(a0, b0, acc00);
    acc01 = MFMA16(a0, b1, acc01);
    acc10 = MFMA16(a1, b0, acc10);
    acc11 = MFMA16(a1, b1, acc11);
  }
  __syncthreads();

  float* Ct = (float*)smem;
  {
    const int rq = (lane >> 4) << 2;
    const int cq = lane & 15;
#pragma unroll
    for (int r = 0; r < 4; ++r) {
      Ct[(mh * 16 + rq + r) * 65 + nh * 16 + cq]            = acc00[r];
      Ct[(mh * 16 + rq + r) * 65 + nh * 16 + 16 + cq]       = acc01[r];
      Ct[((mh + 1) * 16 + rq + r) * 65 + nh * 16 + cq]      = acc10[r];
      Ct[((mh + 1) * 16 + rq + r) * 65 + nh * 16 + 16 + cq] = acc11[r];
    }
  }
  __syncthreads();

  const int r   = tid >> 2;
  const int c0  = (tid & 3) << 4;
  const int row = m0 + r;
  const float* cr = Ct + r * 65;

  if (MODE == 0) {
    u16* crow = (u16*)Cv + (size_t)row * DIM_ + n0;
    float* ssq = (float*)(smem + 16640);
    float ss = 0.f;
#pragma unroll
    for (int i = 0; i < 16; ++i) { const float vv = cr[c0 + i]; ss += vv * vv; }
    ssq[tid] = ss;
    __syncthreads();
    const float tot = ssq[r << 2] + ssq[(r << 2) + 1] + ssq[(r << 2) + 2] + ssq[(r << 2) + 3];
    const float scale = rsqrtf(tot * (1.0f / 64.0f) + EPS_);
    const float tpos = (float)(row & (T_ - 1));
#pragma unroll
    for (int i = 0; i < 16; ++i) {
      const int c = c0 + i;
      const int fi = c & 31;
      const float vlo = cr[fi] * scale;
      const float vhi = cr[fi + 32] * scale;
      const float fr = tpos * powf(10000.0f, -(float)fi * (1.0f / 32.0f));
      float sn, cs;
      sincosf(fr, &sn, &cs);
      const float o = (c < 32) ? (vlo * cs + vhi * sn) : (vhi * cs - vlo * sn);
      crow[c] = f2b(o);
    }
  } else if (MODE == 1) {
    u16* crow = (u16*)Cv + (size_t)row * DIM_ + n0;
    const float lam = lambp[0];
    const float* v1row = v1 + (size_t)row * DIM_ + n0;
#pragma unroll
    for (int i = 0; i < 16; ++i) {
      const int c = c0 + i;
      crow[c] = f2b((1.f - lam) * cr[c] + lam * v1row[c]);
    }
  } else {
    float* crow = (float*)Cv + (size_t)row * DIM_ + n0;
#pragma unroll
    for (int i = 0; i < 16; ++i) crow[c0 + i] = cr[c0 + i];
  }
}

// ---------------------------------------------------------------------------
// gate[n, h] = sigmoid( sum_{j<12} x[n, j] * Wg[h, j] )   (all f32)
// ---------------------------------------------------------------------------
__global__ __launch_bounds__(256) void gate_kernel(
    const float* __restrict__ x, const float* __restrict__ Wg,
    float* __restrict__ gate) {
  const int id = blockIdx.x * 256 + threadIdx.x;
  const int n = id >> 4, h = id & 15;
  const float* xr = x + (size_t)n * DIM_;
  const float* wr = Wg + h * 12;
  float s = 0.f;
#pragma unroll
  for (int j = 0; j < 12; ++j) s += xr[j] * wr[j];
  gate[id] = 1.f / (1.f + __expf(-s));
}

// ---------------------------------------------------------------------------
// MFMA flash attention. Block = (b, h, 64-row q tile); 4 waves x 16 q rows.
// K-tile loop (64 keys): stage K[kpos][hd] and Vt[hd][kpos] to LDS (144B row
// stride), QK^T via MFMA (Q frags in regs), online softmax in C-layout regs,
// P -> per-wave LDS (C-layout scatter, A-layout b128 read), PV via MFMA.
// Causal mask only on the diagonal tile. Epilogue fuses 1/l and gate.
// y aliases q safely (block reads only its own q stripe, at kernel start).
// ---------------------------------------------------------------------------
__global__ __launch_bounds__(256) void attn_mfma(
    const u16* __restrict__ q, const u16* __restrict__ k, const u16* __restrict__ v,
    const float* __restrict__ gate, u16* __restrict__ y) {
  __shared__ __attribute__((aligned(16))) unsigned char smem[27648];
  unsigned char* Ksm = smem;           // 64 rows (kpos) x 144B
  unsigned char* Vsm = smem + 9216;    // 64 rows (hd)   x 144B  (V transposed)
  unsigned char* Psm = smem + 18432;   // 4 waves x 16 rows (q) x 144B

  const int tid  = threadIdx.x;
  const int w    = tid >> 6;
  const int lane = tid & 63;
  const int lo   = lane & 15;
  const int hi   = lane >> 4;
  const int qt   = blockIdx.x & 31;
  const int bh   = blockIdx.x >> 5;
  const int b    = bh >> 4;
  const int h    = bh & 15;
  const int qb   = qt << 6;

  // Q A-fragments, held in registers for the whole kernel (q row = lo)
  const size_t qrow = ((size_t)(b * T_ + qb + (w << 4) + lo)) * DIM_ + h * HD_;
  const bf16x8 qf0 = *(const bf16x8*)(q + qrow + (hi << 3));
  const bf16x8 qf1 = *(const bf16x8*)(q + qrow + 32 + (hi << 3));

  f32x4 o0 = {0.f, 0.f, 0.f, 0.f}, o1 = o0, o2 = o0, o3 = o0;
  float mr[4] = {-1e30f, -1e30f, -1e30f, -1e30f};
  float lr[4] = {0.f, 0.f, 0.f, 0.f};

  const size_t kvbase = ((size_t)(b * T_)) * DIM_ + h * HD_;
  unsigned char* Pw = Psm + w * 2304;

  const int ntiles = qt + 1;
  for (int tix = 0; tix < ntiles; ++tix) {
    const int kb = tix << 6;
    __syncthreads();               // prior iteration's PV reads complete
    // ---- stage K (row-major) and V (transposed) ----
    {
      const int kpos = tid & 63;
      const int hdb0 = (tid >> 6) << 3;          // 0,8,16,24
      const size_t grow = kvbase + (size_t)(kb + kpos) * DIM_;
#pragma unroll
      for (int i = 0; i < 2; ++i) {
        const int hdb = hdb0 + (i << 5);
        const uint4 kk = *(const uint4*)(k + grow + hdb);
        *(uint4*)(Ksm + kpos * 144 + hdb * 2) = kk;
        const uint4 vv = *(const uint4*)(v + grow + hdb);
        const u32 vwords[4] = {vv.x, vv.y, vv.z, vv.w};
#pragma unroll
        for (int j = 0; j < 8; ++j) {
          const u16 ve = (u16)(vwords[j >> 1] >> ((j & 1) << 4));
          *(u16*)(Vsm + (hdb + j) * 144 + kpos * 2) = ve;
        }
      }
    }
    __syncthreads();               // K/Vt staged
    // ---- QK^T ----
    f32x4 sc[4];
#pragma unroll
    for (int nt = 0; nt < 4; ++nt) {
      const unsigned char* kr = Ksm + ((nt << 4) + lo) * 144 + (hi << 4);
      f32x4 s = {0.f, 0.f, 0.f, 0.f};
      s = MFMA16(qf0, *(const bf16x8*)kr, s);
      s = MFMA16(qf1, *(const bf16x8*)(kr + 64), s);
      sc[nt] = s * SCALE_;
    }
    // ---- causal mask (diagonal tile only) ----
    if (tix == qt) {
#pragma unroll
      for (int nt = 0; nt < 4; ++nt)
#pragma unroll
        for (int r = 0; r < 4; ++r)
          if ((nt << 4) + lo > (w << 4) + (hi << 2) + r) sc[nt][r] = -3e38f;
    }
    // ---- online softmax (per reg r = q row (hi*4+r) within wave tile) ----
    float alpha[4];
#pragma unroll
    for (int r = 0; r < 4; ++r) {
      float mx = fmaxf(fmaxf(sc[0][r], sc[1][r]), fmaxf(sc[2][r], sc[3][r]));
      mx = fmaxf(mx, __shfl_xor(mx, 1, 64));
      mx = fmaxf(mx, __shfl_xor(mx, 2, 64));
      mx = fmaxf(mx, __shfl_xor(mx, 4, 64));
      mx = fmaxf(mx, __shfl_xor(mx, 8, 64));
      const float mn = fmaxf(mr[r], mx);
      alpha[r] = __expf(mr[r] - mn);
      mr[r] = mn;
      float ps = 0.f;
#pragma unroll
      for (int nt = 0; nt < 4; ++nt) {
        sc[nt][r] = __expf(sc[nt][r] - mn);
        ps += sc[nt][r];
      }
      ps += __shfl_xor(ps, 1, 64);
      ps += __shfl_xor(ps, 2, 64);
      ps += __shfl_xor(ps, 4, 64);
      ps += __shfl_xor(ps, 8, 64);
      lr[r] = lr[r] * alpha[r] + ps;
    }
#pragma unroll
    for (int r = 0; r < 4; ++r) {
      o0[r] *= alpha[r]; o1[r] *= alpha[r];
      o2[r] *= alpha[r]; o3[r] *= alpha[r];
    }
    // ---- P: C-layout scatter into this wave's LDS region ----
#pragma unroll
    for (int nt = 0; nt < 4; ++nt)
#pragma unroll
      for (int r = 0; r < 4; ++r)
        *(u16*)(Pw + ((hi << 2) + r) * 144 + (((nt << 4) + lo) << 1)) = f2b(sc[nt][r]);
    // ---- PV (P read is intra-wave; Vt staged before barrier) ----
#pragma unroll
    for (int c2 = 0; c2 < 2; ++c2) {
      const bf16x8 pa = *(const bf16x8*)(Pw + lo * 144 + (c2 << 6) + (hi << 4));
      const unsigned char* vb = Vsm + lo * 144 + (c2 << 6) + (hi << 4);
      o0 = MFMA16(pa, *(const bf16x8*)(vb), o0);
      o1 = MFMA16(pa, *(const bf16x8*)(vb + 16 * 144), o1);
      o2 = MFMA16(pa, *(const bf16x8*)(vb + 32 * 144), o2);
      o3 = MFMA16(pa, *(const bf16x8*)(vb + 48 * 144), o3);
    }
  }

  // ---- epilogue: 1/l, gate, bf16 store (y aliases q; reads done) ----
#pragma unroll
  for (int r = 0; r < 4; ++r) {
    const int qr = qb + (w << 4) + (hi << 2) + r;
    const float gv = gate[(size_t)(b * T_ + qr) * H_ + h];
    const float inv = gv / lr[r];
    u16* yrow = y + ((size_t)(b * T_ + qr)) * DIM_ + h * HD_;
    yrow[lo]      = f2b(o0[r] * inv);
    yrow[16 + lo] = f2b(o1[r] * inv);
    yrow[32 + lo] = f2b(o2[r] * inv);
    yrow[48 + lo] = f2b(o3[r] * inv);
  }
}

// ---------------------------------------------------------------------------
extern "C" void kernel_launch(void* const* d_in, const int* in_sizes, int n_in,
                              void* d_out, int out_size, void* d_ws, size_t ws_size,
                              hipStream_t stream) {
  const float* x    = (const float*)d_in[0];
  const float* v1   = (const float*)d_in[1];
  const float* Wq   = (const float*)d_in[2];
  const float* Wk   = (const float*)d_in[3];
  const float* Wv   = (const float*)d_in[4];
  const float* Wp   = (const float*)d_in[5];
  const float* Wg   = (const float*)d_in[6];
  const float* lamb = (const float*)d_in[7];

  const size_t NX = (size_t)NROW * DIM_;   // 4M elements

  u16* q = (u16*)d_ws;                     // also y (in-place)
  u16* k = q + NX;
  u16* v = k + NX;
  float* gate = (float*)(v + NX);          // total ws: 24.25 MB

  const dim3 bb(256);
  const dim3 gg(NROW / 64, DIM_ / 64);

  gemm_ep<0, false><<<gg, bb, 0, stream>>>(x, Wq, q, nullptr, nullptr);
  gemm_ep<0, false><<<gg, bb, 0, stream>>>(x, Wk, k, nullptr, nullptr);
  gemm_ep<1, false><<<gg, bb, 0, stream>>>(x, Wv, v, v1, lamb);
  gate_kernel<<<dim3(NROW * H_ / 256), bb, 0, stream>>>(x, Wg, gate);
  attn_mfma<<<dim3(B_ * H_ * (T_ / 64)), bb, 0, stream>>>(q, k, v, gate, q);
  gemm_ep<2, true><<<gg, bb, 0, stream>>>(q, Wp, (float*)d_out, nullptr, nullptr);
}

// Round 6
// 333.712 us; speedup vs baseline: 6.2223x; 1.4677x over previous
//
#include <hip/hip_runtime.h>
#include <math.h>

// ---------------------------------------------------------------------------
// CausalSelfAttention fused pipeline, MI355X gfx950.  Round 6.
// r5: 490us. attn 141us (MfmaUtil 5%, 4.9M bank conflicts), GEMMs ~340us
// (VALU-staging-bound). This round:
//  * GEMM: 128x128 tile BK=64, cvt_pk_bf16_f32 staging, fused QKV dispatch,
//    reg-level epilogues (rmsnorm+rope via shfl, v written TRANSPOSED [bh][d][t]).
//  * attn: S^T = K.Q^T form -> P stays in registers (shfl transpose to PV
//    B-operand), no P/V LDS scatters, qt-descending launch order.
// Workspace: q(=y) 8MB | k 8MB | vt 8MB | gate 256KB.
// ---------------------------------------------------------------------------

#define B_    2
#define T_    2048
#define DIM_  1024
#define H_    16
#define HD_   64
#define NROW  (B_ * T_)
#define EPS_  1.1920929e-07f
#define SCALE_ 0.1f
#define LOG2_10K 13.287712379549449f

typedef unsigned short u16;
typedef unsigned int   u32;
typedef __bf16 bf16x8 __attribute__((ext_vector_type(8)));
typedef __bf16 bf16x2 __attribute__((ext_vector_type(2)));
typedef float  f32x4  __attribute__((ext_vector_type(4)));

__device__ __forceinline__ u16 f2b(float f) {
  u32 u = __float_as_uint(f);
  u += 0x7fffu + ((u >> 16) & 1u);       // RNE
  return (u16)(u >> 16);
}
__device__ __forceinline__ u32 pk2(float a, float b) {
#if __has_builtin(__builtin_amdgcn_cvt_pk_bf16_f32)
  bf16x2 r = __builtin_amdgcn_cvt_pk_bf16_f32(a, b);
  return __builtin_bit_cast(u32, r);
#else
  return (u32)f2b(a) | ((u32)f2b(b) << 16);
#endif
}
#define MFMA16(a,b,c) __builtin_amdgcn_mfma_f32_16x16x32_bf16((a),(b),(c),0,0,0)

// ---------------------------------------------------------------------------
// Big-tile GEMM: C[row,n] = sum_k A[row,k]*W[n,k].  128x128 block, BK=64,
// 4 waves x (64x64). Fragment-order LDS: slot S=(msub*2+khalf)*64+l holds
// row msub*16+(l&15), k khalf*32+(l>>4)*8 -> b128 write & read at linear*16.
// IS_PROJ=false: A=x f32, grid (32,24): by>>3 = 0:q(rope) 1:k(rope) 2:v(blend,
// transposed store).  IS_PROJ=true: A=y bf16, W=Wp, f32 out, grid (32,8).
// ---------------------------------------------------------------------------
template <bool IS_PROJ>
__global__ __launch_bounds__(256) void gemm_big(
    const void* __restrict__ Av,
    const float* __restrict__ W0, const float* __restrict__ W1,
    const float* __restrict__ W2,
    u16* __restrict__ qo, u16* __restrict__ ko, u16* __restrict__ vto,
    float* __restrict__ fo,
    const float* __restrict__ v1, const float* __restrict__ lambp) {
  __shared__ __attribute__((aligned(16))) unsigned char smem[32768];
  const int tid  = threadIdx.x;
  const int wv   = tid >> 6;
  const int lane = tid & 63;
  const int lo = lane & 15, hi = lane >> 4;
  const int m0 = blockIdx.x << 7;
  const int by = blockIdx.y;
  const int mode = IS_PROJ ? 3 : (by >> 3);
  const int n0 = IS_PROJ ? (by << 7) : ((by & 7) << 7);
  const float* W = IS_PROJ ? W0 : (mode == 0 ? W0 : (mode == 1 ? W1 : W2));

  // staging constants (slot = tid + 256*i)
  const int sl  = tid & 63;
  const int skh = (tid >> 6) & 1;
  const int sm0 = tid >> 7;                          // 0/1
  const int srow = sl & 15;
  const int skk  = skh * 32 + ((sl >> 4) << 3);      // k-off within 64

  f32x4 acc[4][4];
#pragma unroll
  for (int i = 0; i < 4; ++i)
#pragma unroll
    for (int j = 0; j < 4; ++j) acc[i][j] = (f32x4){0.f, 0.f, 0.f, 0.f};

  const int wm = wv & 1, wn = wv >> 1;

  for (int kc = 0; kc < DIM_; kc += 64) {
    uint4 ap[4], bp[4];
#pragma unroll
    for (int i = 0; i < 4; ++i) {
      const int row = (sm0 + 2 * i) * 16 + srow;
      if constexpr (IS_PROJ) {
        ap[i] = *(const uint4*)((const u16*)Av + (size_t)(m0 + row) * DIM_ + kc + skk);
      } else {
        const float* p = (const float*)Av + (size_t)(m0 + row) * DIM_ + kc + skk;
        const float4 f0 = *(const float4*)p;
        const float4 f1 = *(const float4*)(p + 4);
        ap[i].x = pk2(f0.x, f0.y); ap[i].y = pk2(f0.z, f0.w);
        ap[i].z = pk2(f1.x, f1.y); ap[i].w = pk2(f1.z, f1.w);
      }
      const float* pw = W + (size_t)(n0 + row) * DIM_ + kc + skk;
      const float4 g0 = *(const float4*)pw;
      const float4 g1 = *(const float4*)(pw + 4);
      bp[i].x = pk2(g0.x, g0.y); bp[i].y = pk2(g0.z, g0.w);
      bp[i].z = pk2(g1.x, g1.y); bp[i].w = pk2(g1.z, g1.w);
    }
    __syncthreads();                         // prior iter's frag reads done
#pragma unroll
    for (int i = 0; i < 4; ++i) {
      *(uint4*)(smem + (((size_t)tid + 256 * i) << 4)) = ap[i];
      *(uint4*)(smem + 16384 + (((size_t)tid + 256 * i) << 4)) = bp[i];
    }
    __syncthreads();                         // tile staged
#pragma unroll
    for (int kh = 0; kh < 2; ++kh) {
      bf16x8 af[4], bf[4];
#pragma unroll
      for (int mt = 0; mt < 4; ++mt)
        af[mt] = *(const bf16x8*)(smem + ((((wm * 4 + mt) * 2 + kh) * 64 + lane) << 4));
#pragma unroll
      for (int nt = 0; nt < 4; ++nt)
        bf[nt] = *(const bf16x8*)(smem + 16384 + ((((wn * 4 + nt) * 2 + kh) * 64 + lane) << 4));
#pragma unroll
      for (int mt = 0; mt < 4; ++mt)
#pragma unroll
        for (int nt = 0; nt < 4; ++nt)
          acc[mt][nt] = MFMA16(af[mt], bf[nt], acc[mt][nt]);
    }
  }

  // ---- epilogue (from accs, no LDS) ----
  const int head = (n0 >> 6) + wn;           // qkv modes: one head per wave
  if (mode <= 1) {
    u16* C = (mode == 0) ? qo : ko;
    const float if0 = exp2f(-(float)lo * (LOG2_10K / 32.f));
    const float if1 = exp2f(-(float)(lo + 16) * (LOG2_10K / 32.f));
#pragma unroll
    for (int mt = 0; mt < 4; ++mt)
#pragma unroll
      for (int r = 0; r < 4; ++r) {
        float ss = 0.f;
#pragma unroll
        for (int nt = 0; nt < 4; ++nt) { const float v = acc[mt][nt][r]; ss += v * v; }
        ss += __shfl_xor(ss, 1, 64); ss += __shfl_xor(ss, 2, 64);
        ss += __shfl_xor(ss, 4, 64); ss += __shfl_xor(ss, 8, 64);
        const float scl = rsqrtf(ss * (1.f / 64.f) + EPS_);
        const int row_g = m0 + wm * 64 + mt * 16 + hi * 4 + r;
        const float tpos = (float)(row_g & (T_ - 1));
        float sn0, cs0, sn1, cs1;
        sincosf(tpos * if0, &sn0, &cs0);
        sincosf(tpos * if1, &sn1, &cs1);
        u16* crow = C + (size_t)row_g * DIM_ + head * HD_;
        const float x10 = acc[mt][0][r] * scl, x11 = acc[mt][1][r] * scl;
        const float x20 = acc[mt][2][r] * scl, x21 = acc[mt][3][r] * scl;
        crow[lo]      = f2b(x10 * cs0 + x20 * sn0);
        crow[16 + lo] = f2b(x11 * cs1 + x21 * sn1);
        crow[32 + lo] = f2b(x20 * cs0 - x10 * sn0);
        crow[48 + lo] = f2b(x21 * cs1 - x11 * sn1);
      }
  } else if (mode == 2) {
    const float lam = lambp[0];
#pragma unroll
    for (int mt = 0; mt < 4; ++mt)
#pragma unroll
      for (int r = 0; r < 4; ++r) {
        const int row_g = m0 + wm * 64 + mt * 16 + hi * 4 + r;
        const int bb = row_g >> 11, tt = row_g & (T_ - 1);
        const int bh = bb * H_ + head;
        const float* v1r = v1 + (size_t)row_g * DIM_ + head * HD_;
#pragma unroll
        for (int nt = 0; nt < 4; ++nt) {
          const int d = nt * 16 + lo;
          const float ov = (1.f - lam) * acc[mt][nt][r] + lam * v1r[d];
          vto[((size_t)(bh * HD_ + d)) * T_ + tt] = f2b(ov);   // transposed store
        }
      }
  } else {
#pragma unroll
    for (int mt = 0; mt < 4; ++mt)
#pragma unroll
      for (int r = 0; r < 4; ++r) {
        const int row_g = m0 + wm * 64 + mt * 16 + hi * 4 + r;
        float* orow = fo + (size_t)row_g * DIM_ + n0 + wn * 64;
#pragma unroll
        for (int nt = 0; nt < 4; ++nt) orow[nt * 16 + lo] = acc[mt][nt][r];
      }
  }
}

// ---------------------------------------------------------------------------
// gate[n,h] = sigmoid( sum_{j<12} x[n,j]*Wg[h,j] )
// ---------------------------------------------------------------------------
__global__ __launch_bounds__(256) void gate_kernel(
    const float* __restrict__ x, const float* __restrict__ Wg,
    float* __restrict__ gate) {
  const int id = blockIdx.x * 256 + threadIdx.x;
  const int n = id >> 4, h = id & 15;
  const float* xr = x + (size_t)n * DIM_;
  const float* wr = Wg + h * 12;
  float s = 0.f;
#pragma unroll
  for (int j = 0; j < 12; ++j) s += xr[j] * wr[j];
  gate[id] = 1.f / (1.f + __expf(-s));
}

// ---------------------------------------------------------------------------
// MFMA flash attention, S^T form.  Block = (b,h,64-q tile), 4 waves x 16 q.
// S^T[key][q] = K.Q^T : A = K tile from LDS (fragment order), B = Q in regs.
// Online softmax per q-column (lane lo), replicated across hi groups.
// PV: O^T[d][q] = VT.P^T : A = VT tile from LDS (v pre-transposed [bh][d][t]),
// B = P built from S^T C-layout registers via 16 shfl + cndmask (NO P LDS).
// qt descending over blockIdx so longest blocks launch first.
// ---------------------------------------------------------------------------
__global__ __launch_bounds__(256) void attn3(
    const u16* __restrict__ q, const u16* __restrict__ k, const u16* __restrict__ vt,
    const float* __restrict__ gate, u16* __restrict__ y) {
  __shared__ __attribute__((aligned(16))) unsigned char smem[16384];
  const int tid = threadIdx.x;
  const int wv = tid >> 6, lane = tid & 63, lo = lane & 15, hi = lane >> 4;
  const int idx = blockIdx.x;
  const int qt = 31 - (idx >> 5);
  const int bh = idx & 31;
  const int b = bh >> 4, h = bh & 15;
  const int qb = qt << 6;

  const int qrow = b * T_ + qb + wv * 16 + lo;
  const u16* qp = q + (size_t)qrow * DIM_ + h * HD_;
  const bf16x8 qf0 = *(const bf16x8*)(qp + hi * 8);
  const bf16x8 qf1 = *(const bf16x8*)(qp + 32 + hi * 8);

  f32x4 o[4];
#pragma unroll
  for (int i = 0; i < 4; ++i) o[i] = (f32x4){0.f, 0.f, 0.f, 0.f};
  float mrun = -1e30f, lrun = 0.f;

  // staging: K slots {tid, tid+256}, VT slots {tid, tid+256}
  const int sl = tid & 63, skh = (tid >> 6) & 1, st0 = tid >> 7;
  const int srow = sl & 15, skk = skh * 32 + ((sl >> 4) << 3);
  const u16* kg0 = k + ((size_t)(b * T_ + st0 * 16 + srow)) * DIM_ + h * HD_ + skk;
  const u16* kg1 = kg0 + (size_t)32 * DIM_;
  const u16* vg0 = vt + ((size_t)(bh * HD_ + st0 * 16 + srow)) * T_ + skk;
  const u16* vg1 = vg0 + (size_t)32 * T_;

  uint4 kr0 = *(const uint4*)kg0, kr1 = *(const uint4*)kg1;
  uint4 vr0 = *(const uint4*)vg0, vr1 = *(const uint4*)vg1;

  const int off0 = tid << 4, off1 = (tid + 256) << 4;

  for (int tix = 0; tix <= qt; ++tix) {
    __syncthreads();                     // prior iter's LDS reads done
    *(uint4*)(smem + off0) = kr0;
    *(uint4*)(smem + off1) = kr1;
    *(uint4*)(smem + 8192 + off0) = vr0;
    *(uint4*)(smem + 8192 + off1) = vr1;
    if (tix < qt) {                      // prefetch next tile
      const size_t ko = (size_t)(tix + 1) * 64 * DIM_;
      const size_t vo = (size_t)(tix + 1) * 64;
      kr0 = *(const uint4*)(kg0 + ko); kr1 = *(const uint4*)(kg1 + ko);
      vr0 = *(const uint4*)(vg0 + vo); vr1 = *(const uint4*)(vg1 + vo);
    }
    __syncthreads();                     // tile staged

    // ---- S^T = K . Q^T ----
    f32x4 stl[4];
#pragma unroll
    for (int kt = 0; kt < 4; ++kt) stl[kt] = (f32x4){0.f, 0.f, 0.f, 0.f};
#pragma unroll
    for (int kh = 0; kh < 2; ++kh) {
      const bf16x8 qb_ = kh ? qf1 : qf0;
#pragma unroll
      for (int kt = 0; kt < 4; ++kt) {
        const bf16x8 af = *(const bf16x8*)(smem + (((kt * 2 + kh) * 64 + lane) << 4));
        stl[kt] = MFMA16(af, qb_, stl[kt]);
      }
    }
    // ---- scale + causal mask (diag tile only) ----
    const bool diag = (tix == qt);
#pragma unroll
    for (int kt = 0; kt < 4; ++kt)
#pragma unroll
      for (int r = 0; r < 4; ++r) {
        float s = stl[kt][r] * SCALE_;
        if (diag && (kt * 16 + hi * 4 + r > wv * 16 + lo)) s = -3e38f;
        stl[kt][r] = s;
      }
    // ---- online softmax (per q = lo; reduce across hi via xor 16,32) ----
    float mx = stl[0][0];
#pragma unroll
    for (int kt = 0; kt < 4; ++kt)
#pragma unroll
      for (int r = 0; r < 4; ++r) mx = fmaxf(mx, stl[kt][r]);
    mx = fmaxf(mx, __shfl_xor(mx, 16, 64));
    mx = fmaxf(mx, __shfl_xor(mx, 32, 64));
    const float mn = fmaxf(mrun, mx);
    const float alpha = __expf(mrun - mn);
    mrun = mn;
    float ps = 0.f;
#pragma unroll
    for (int kt = 0; kt < 4; ++kt)
#pragma unroll
      for (int r = 0; r < 4; ++r) { stl[kt][r] = __expf(stl[kt][r] - mn); ps += stl[kt][r]; }
    ps += __shfl_xor(ps, 16, 64);
    ps += __shfl_xor(ps, 32, 64);
    lrun = lrun * alpha + ps;
#pragma unroll
    for (int dt = 0; dt < 4; ++dt) o[dt] *= alpha;
    // ---- P to bf16 pairs, then PV via shfl-built B-operand ----
    u32 pkv[4][2];
#pragma unroll
    for (int kt = 0; kt < 4; ++kt) {
      pkv[kt][0] = pk2(stl[kt][0], stl[kt][1]);
      pkv[kt][1] = pk2(stl[kt][2], stl[kt][3]);
    }
#pragma unroll
    for (int kh = 0; kh < 2; ++kh) {
      uint4 w4;
      u32* w4p = (u32*)&w4;
#pragma unroll
      for (int wd = 0; wd < 4; ++wd) {
        const int src = (2 * (hi & 1) + (wd >> 1)) * 16 + lo;
        const u32 a  = (u32)__shfl((int)pkv[2 * kh][wd & 1], src, 64);
        const u32 bb = (u32)__shfl((int)pkv[2 * kh + 1][wd & 1], src, 64);
        w4p[wd] = (hi < 2) ? a : bb;
      }
      const bf16x8 pf = __builtin_bit_cast(bf16x8, w4);
#pragma unroll
      for (int dt = 0; dt < 4; ++dt) {
        const bf16x8 vf = *(const bf16x8*)(smem + 8192 + (((dt * 2 + kh) * 64 + lane) << 4));
        o[dt] = MFMA16(vf, pf, o[dt]);
      }
    }
  }

  // ---- epilogue: gate/l, pack r-quads, 8B stores (y aliases q: safe) ----
  const float inv = gate[(size_t)qrow * H_ + h] / lrun;
  u16* yrow = y + (size_t)qrow * DIM_ + h * HD_;
#pragma unroll
  for (int dt = 0; dt < 4; ++dt) {
    ushort4 pq;
    pq.x = f2b(o[dt][0] * inv); pq.y = f2b(o[dt][1] * inv);
    pq.z = f2b(o[dt][2] * inv); pq.w = f2b(o[dt][3] * inv);
    *(ushort4*)(yrow + dt * 16 + hi * 4) = pq;
  }
}

// ---------------------------------------------------------------------------
extern "C" void kernel_launch(void* const* d_in, const int* in_sizes, int n_in,
                              void* d_out, int out_size, void* d_ws, size_t ws_size,
                              hipStream_t stream) {
  const float* x    = (const float*)d_in[0];
  const float* v1   = (const float*)d_in[1];
  const float* Wq   = (const float*)d_in[2];
  const float* Wk   = (const float*)d_in[3];
  const float* Wv   = (const float*)d_in[4];
  const float* Wp   = (const float*)d_in[5];
  const float* Wg   = (const float*)d_in[6];
  const float* lamb = (const float*)d_in[7];

  const size_t NX = (size_t)NROW * DIM_;

  u16* q  = (u16*)d_ws;                    // also y (in-place)
  u16* k  = q + NX;
  u16* vt = k + NX;                        // [bh][d][t]
  float* gate = (float*)(vt + NX);         // total ws: 24.25 MB

  const dim3 bb(256);

  gemm_big<false><<<dim3(NROW / 128, 24), bb, 0, stream>>>(
      x, Wq, Wk, Wv, q, k, vt, nullptr, v1, lamb);
  gate_kernel<<<dim3(NROW * H_ / 256), bb, 0, stream>>>(x, Wg, gate);
  attn3<<<dim3(B_ * H_ * (T_ / 64)), bb, 0, stream>>>(q, k, vt, gate, q);
  gemm_big<true><<<dim3(NROW / 128, 8), bb, 0, stream>>>(
      q, Wp, nullptr, nullptr, nullptr, nullptr, nullptr, (float*)d_out,
      nullptr, nullptr);
}

// Round 7
// 250.259 us; speedup vs baseline: 8.2972x; 1.3335x over previous
//
#include <hip/hip_runtime.h>
#include <math.h>

// ---------------------------------------------------------------------------
// CausalSelfAttention fused pipeline, MI355X gfx950.  Round 7.
// r6: 334us; QKV gemm 180us at MfmaUtil 5.8% (latency-bound cvt staging).
// This round: one-time f32->bf16 convert pass (x, Wq,Wk,Wv,Wp), then all
// GEMMs use the m97-verified structure: 128x128 tile, BK=32, fragment-order
// LDS via global_load_lds width=16, 2-barrier K-loop. Register epilogues
// (rmsnorm+rope / lamb-blend+transposed-v / f32-out) unchanged from r6.
// attn3 (S^T-form MFMA flash, P in registers) and gate unchanged.
// Workspace: q(=y) 8MB | k 8MB | vt 8MB | xb 8MB | w[4]b 8MB | gate 256KB.
// ---------------------------------------------------------------------------

#define B_    2
#define T_    2048
#define DIM_  1024
#define H_    16
#define HD_   64
#define NROW  (B_ * T_)
#define EPS_  1.1920929e-07f
#define SCALE_ 0.1f
#define LOG2_10K 13.287712379549449f

typedef unsigned short u16;
typedef unsigned int   u32;
typedef __bf16 bf16x8 __attribute__((ext_vector_type(8)));
typedef __bf16 bf16x2 __attribute__((ext_vector_type(2)));
typedef float  f32x4  __attribute__((ext_vector_type(4)));

__device__ __forceinline__ u16 f2b(float f) {
  u32 u = __float_as_uint(f);
  u += 0x7fffu + ((u >> 16) & 1u);       // RNE
  return (u16)(u >> 16);
}
__device__ __forceinline__ u32 pk2(float a, float b) {
#if __has_builtin(__builtin_amdgcn_cvt_pk_bf16_f32)
  bf16x2 r = __builtin_amdgcn_cvt_pk_bf16_f32(a, b);
  return __builtin_bit_cast(u32, r);
#else
  return (u32)f2b(a) | ((u32)f2b(b) << 16);
#endif
}
__device__ __forceinline__ void load16_lds(const u16* g, void* l) {
  __builtin_amdgcn_global_load_lds(
      (const __attribute__((address_space(1))) void*)g,
      (__attribute__((address_space(3))) void*)l, 16, 0, 0);
}
#define MFMA16(a,b,c) __builtin_amdgcn_mfma_f32_16x16x32_bf16((a),(b),(c),0,0,0)

// ---------------------------------------------------------------------------
// Convert pass: x (4M) and Wq/Wk/Wv/Wp (1M each) f32 -> bf16.
// One grid-stride-free kernel over 2M float4 groups.
// ---------------------------------------------------------------------------
__global__ __launch_bounds__(256) void convert_all(
    const float* __restrict__ x, const float* __restrict__ Wq,
    const float* __restrict__ Wk, const float* __restrict__ Wv,
    const float* __restrict__ Wp,
    u16* __restrict__ xb, u16* __restrict__ wb /* wqb|wkb|wvb|wpb */) {
  const int i = blockIdx.x * 256 + threadIdx.x;       // 0 .. 2M-1 groups
  const float* src;
  u16* dst;
  int off;
  if (i < 1048576)       { src = x;  dst = xb;            off = i; }
  else if (i < 1310720)  { src = Wq; dst = wb;            off = i - 1048576; }
  else if (i < 1572864)  { src = Wk; dst = wb + 1048576;  off = i - 1310720; }
  else if (i < 1835008)  { src = Wv; dst = wb + 2097152;  off = i - 1572864; }
  else                   { src = Wp; dst = wb + 3145728;  off = i - 1835008; }
  const float4 f = ((const float4*)src)[off];
  uint2 o;
  o.x = pk2(f.x, f.y);
  o.y = pk2(f.z, f.w);
  ((uint2*)dst)[off] = o;
}

// ---------------------------------------------------------------------------
// m97-structure GEMM: C[row,n] = sum_k A[row,k]*W[n,k], all-bf16 inputs.
// 128x128 block tile, BK=32, 4 waves x (64x64 via 4x4 16x16x32 accs).
// LDS in fragment order: subtile s (16 rows x 32 k), slot l holds
// row s*16+(l&15), k (l>>4)*8..+7  ->  global_load_lds lands lane l's 16B at
// base+l*16; consumer ds_read_b128 at (s*64+lane)*16. Wave w stages A and B
// subtiles {2w, 2w+1}. 2-barrier K-loop (m97-verified ~874 TF structure).
// IS_PROJ=false: grid (32,24), mode=by>>3: 0 q(rope) 1 k(rope) 2 v(blend,
//   transposed [bh][d][t] store); W = Wb + mode*1M.
// IS_PROJ=true: grid (32,8), W=Wb, f32 out.
// ---------------------------------------------------------------------------
template <bool IS_PROJ>
__global__ __launch_bounds__(256) void gemm97(
    const u16* __restrict__ Ab, const u16* __restrict__ Wb,
    u16* __restrict__ qo, u16* __restrict__ ko, u16* __restrict__ vto,
    float* __restrict__ fo, const float* __restrict__ v1,
    const float* __restrict__ lambp) {
  __shared__ __attribute__((aligned(16))) u16 Asm[8 * 512];   // 8 KB
  __shared__ __attribute__((aligned(16))) u16 Bsm[8 * 512];   // 8 KB
  const int tid  = threadIdx.x;
  const int w    = tid >> 6;
  const int lane = tid & 63;
  const int lo = lane & 15, hi = lane >> 4;
  const int m0 = blockIdx.x << 7;
  const int by = blockIdx.y;
  const int mode = IS_PROJ ? 3 : (by >> 3);
  const int n0 = IS_PROJ ? (by << 7) : ((by & 7) << 7);
  const u16* W = IS_PROJ ? Wb : (Wb + (size_t)mode * (DIM_ * DIM_));

  const int wm = w & 1, wn = w >> 1;

  // staging pointers: wave w stages subtiles 2w, 2w+1 of A and B
  const u16* agA0 = Ab + (size_t)(m0 + (2 * w + 0) * 16 + lo) * DIM_ + (hi << 3);
  const u16* agA1 = Ab + (size_t)(m0 + (2 * w + 1) * 16 + lo) * DIM_ + (hi << 3);
  const u16* agB0 = W  + (size_t)(n0 + (2 * w + 0) * 16 + lo) * DIM_ + (hi << 3);
  const u16* agB1 = W  + (size_t)(n0 + (2 * w + 1) * 16 + lo) * DIM_ + (hi << 3);
  u16* ldsA0 = Asm + (2 * w + 0) * 512;
  u16* ldsA1 = Asm + (2 * w + 1) * 512;
  u16* ldsB0 = Bsm + (2 * w + 0) * 512;
  u16* ldsB1 = Bsm + (2 * w + 1) * 512;

  f32x4 acc[4][4];
#pragma unroll
  for (int i = 0; i < 4; ++i)
#pragma unroll
    for (int j = 0; j < 4; ++j) acc[i][j] = (f32x4){0.f, 0.f, 0.f, 0.f};

  for (int kc = 0; kc < DIM_; kc += 32) {
    load16_lds(agA0, ldsA0);
    load16_lds(agA1, ldsA1);
    load16_lds(agB0, ldsB0);
    load16_lds(agB1, ldsB1);
    agA0 += 32; agA1 += 32; agB0 += 32; agB1 += 32;
    __syncthreads();                 // drains vmcnt: staged tile visible
    bf16x8 af[4], bfr[4];
#pragma unroll
    for (int mt = 0; mt < 4; ++mt)
      af[mt] = *(const bf16x8*)(Asm + (((wm * 4 + mt) * 64 + lane) << 3));
#pragma unroll
    for (int nt = 0; nt < 4; ++nt)
      bfr[nt] = *(const bf16x8*)(Bsm + (((wn * 4 + nt) * 64 + lane) << 3));
#pragma unroll
    for (int mt = 0; mt < 4; ++mt)
#pragma unroll
      for (int nt = 0; nt < 4; ++nt)
        acc[mt][nt] = MFMA16(af[mt], bfr[nt], acc[mt][nt]);
    __syncthreads();                 // frag reads done before next staging
  }

  // ---- register epilogues (r6-verified) ----
  const int head = (n0 >> 6) + wn;
  if (mode <= 1) {
    u16* C = (mode == 0) ? qo : ko;
    const float if0 = exp2f(-(float)lo * (LOG2_10K / 32.f));
    const float if1 = exp2f(-(float)(lo + 16) * (LOG2_10K / 32.f));
#pragma unroll
    for (int mt = 0; mt < 4; ++mt)
#pragma unroll
      for (int r = 0; r < 4; ++r) {
        float ss = 0.f;
#pragma unroll
        for (int nt = 0; nt < 4; ++nt) { const float v = acc[mt][nt][r]; ss += v * v; }
        ss += __shfl_xor(ss, 1, 64); ss += __shfl_xor(ss, 2, 64);
        ss += __shfl_xor(ss, 4, 64); ss += __shfl_xor(ss, 8, 64);
        const float scl = rsqrtf(ss * (1.f / 64.f) + EPS_);
        const int row_g = m0 + wm * 64 + mt * 16 + hi * 4 + r;
        const float tpos = (float)(row_g & (T_ - 1));
        float sn0, cs0, sn1, cs1;
        sincosf(tpos * if0, &sn0, &cs0);
        sincosf(tpos * if1, &sn1, &cs1);
        u16* crow = C + (size_t)row_g * DIM_ + head * HD_;
        const float x10 = acc[mt][0][r] * scl, x11 = acc[mt][1][r] * scl;
        const float x20 = acc[mt][2][r] * scl, x21 = acc[mt][3][r] * scl;
        crow[lo]      = f2b(x10 * cs0 + x20 * sn0);
        crow[16 + lo] = f2b(x11 * cs1 + x21 * sn1);
        crow[32 + lo] = f2b(x20 * cs0 - x10 * sn0);
        crow[48 + lo] = f2b(x21 * cs1 - x11 * sn1);
      }
  } else if (mode == 2) {
    const float lam = lambp[0];
#pragma unroll
    for (int mt = 0; mt < 4; ++mt)
#pragma unroll
      for (int r = 0; r < 4; ++r) {
        const int row_g = m0 + wm * 64 + mt * 16 + hi * 4 + r;
        const int bb = row_g >> 11, tt = row_g & (T_ - 1);
        const int bh = bb * H_ + head;
        const float* v1r = v1 + (size_t)row_g * DIM_ + head * HD_;
#pragma unroll
        for (int nt = 0; nt < 4; ++nt) {
          const int d = nt * 16 + lo;
          const float ov = (1.f - lam) * acc[mt][nt][r] + lam * v1r[d];
          vto[((size_t)(bh * HD_ + d)) * T_ + tt] = f2b(ov);   // transposed
        }
      }
  } else {
#pragma unroll
    for (int mt = 0; mt < 4; ++mt)
#pragma unroll
      for (int r = 0; r < 4; ++r) {
        const int row_g = m0 + wm * 64 + mt * 16 + hi * 4 + r;
        float* orow = fo + (size_t)row_g * DIM_ + n0 + wn * 64;
#pragma unroll
        for (int nt = 0; nt < 4; ++nt) orow[nt * 16 + lo] = acc[mt][nt][r];
      }
  }
}

// ---------------------------------------------------------------------------
// gate[n,h] = sigmoid( sum_{j<12} x[n,j]*Wg[h,j] )
// ---------------------------------------------------------------------------
__global__ __launch_bounds__(256) void gate_kernel(
    const float* __restrict__ x, const float* __restrict__ Wg,
    float* __restrict__ gate) {
  const int id = blockIdx.x * 256 + threadIdx.x;
  const int n = id >> 4, h = id & 15;
  const float* xr = x + (size_t)n * DIM_;
  const float* wr = Wg + h * 12;
  float s = 0.f;
#pragma unroll
  for (int j = 0; j < 12; ++j) s += xr[j] * wr[j];
  gate[id] = 1.f / (1.f + __expf(-s));
}

// ---------------------------------------------------------------------------
// MFMA flash attention, S^T form (r6-verified). Block = (b,h,64-q tile).
// ---------------------------------------------------------------------------
__global__ __launch_bounds__(256) void attn3(
    const u16* __restrict__ q, const u16* __restrict__ k, const u16* __restrict__ vt,
    const float* __restrict__ gate, u16* __restrict__ y) {
  __shared__ __attribute__((aligned(16))) unsigned char smem[16384];
  const int tid = threadIdx.x;
  const int wv = tid >> 6, lane = tid & 63, lo = lane & 15, hi = lane >> 4;
  const int idx = blockIdx.x;
  const int qt = 31 - (idx >> 5);
  const int bh = idx & 31;
  const int b = bh >> 4, h = bh & 15;
  const int qb = qt << 6;

  const int qrow = b * T_ + qb + wv * 16 + lo;
  const u16* qp = q + (size_t)qrow * DIM_ + h * HD_;
  const bf16x8 qf0 = *(const bf16x8*)(qp + hi * 8);
  const bf16x8 qf1 = *(const bf16x8*)(qp + 32 + hi * 8);

  f32x4 o[4];
#pragma unroll
  for (int i = 0; i < 4; ++i) o[i] = (f32x4){0.f, 0.f, 0.f, 0.f};
  float mrun = -1e30f, lrun = 0.f;

  const int sl = tid & 63, skh = (tid >> 6) & 1, st0 = tid >> 7;
  const int srow = sl & 15, skk = skh * 32 + ((sl >> 4) << 3);
  const u16* kg0 = k + ((size_t)(b * T_ + st0 * 16 + srow)) * DIM_ + h * HD_ + skk;
  const u16* kg1 = kg0 + (size_t)32 * DIM_;
  const u16* vg0 = vt + ((size_t)(bh * HD_ + st0 * 16 + srow)) * T_ + skk;
  const u16* vg1 = vg0 + (size_t)32 * T_;

  uint4 kr0 = *(const uint4*)kg0, kr1 = *(const uint4*)kg1;
  uint4 vr0 = *(const uint4*)vg0, vr1 = *(const uint4*)vg1;

  const int off0 = tid << 4, off1 = (tid + 256) << 4;

  for (int tix = 0; tix <= qt; ++tix) {
    __syncthreads();
    *(uint4*)(smem + off0) = kr0;
    *(uint4*)(smem + off1) = kr1;
    *(uint4*)(smem + 8192 + off0) = vr0;
    *(uint4*)(smem + 8192 + off1) = vr1;
    if (tix < qt) {
      const size_t ko = (size_t)(tix + 1) * 64 * DIM_;
      const size_t vo = (size_t)(tix + 1) * 64;
      kr0 = *(const uint4*)(kg0 + ko); kr1 = *(const uint4*)(kg1 + ko);
      vr0 = *(const uint4*)(vg0 + vo); vr1 = *(const uint4*)(vg1 + vo);
    }
    __syncthreads();

    f32x4 stl[4];
#pragma unroll
    for (int kt = 0; kt < 4; ++kt) stl[kt] = (f32x4){0.f, 0.f, 0.f, 0.f};
#pragma unroll
    for (int kh = 0; kh < 2; ++kh) {
      const bf16x8 qb_ = kh ? qf1 : qf0;
#pragma unroll
      for (int kt = 0; kt < 4; ++kt) {
        const bf16x8 af = *(const bf16x8*)(smem + (((kt * 2 + kh) * 64 + lane) << 4));
        stl[kt] = MFMA16(af, qb_, stl[kt]);
      }
    }
    const bool diag = (tix == qt);
#pragma unroll
    for (int kt = 0; kt < 4; ++kt)
#pragma unroll
      for (int r = 0; r < 4; ++r) {
        float s = stl[kt][r] * SCALE_;
        if (diag && (kt * 16 + hi * 4 + r > wv * 16 + lo)) s = -3e38f;
        stl[kt][r] = s;
      }
    float mx = stl[0][0];
#pragma unroll
    for (int kt = 0; kt < 4; ++kt)
#pragma unroll
      for (int r = 0; r < 4; ++r) mx = fmaxf(mx, stl[kt][r]);
    mx = fmaxf(mx, __shfl_xor(mx, 16, 64));
    mx = fmaxf(mx, __shfl_xor(mx, 32, 64));
    const float mn = fmaxf(mrun, mx);
    const float alpha = __expf(mrun - mn);
    mrun = mn;
    float ps = 0.f;
#pragma unroll
    for (int kt = 0; kt < 4; ++kt)
#pragma unroll
      for (int r = 0; r < 4; ++r) { stl[kt][r] = __expf(stl[kt][r] - mn); ps += stl[kt][r]; }
    ps += __shfl_xor(ps, 16, 64);
    ps += __shfl_xor(ps, 32, 64);
    lrun = lrun * alpha + ps;
#pragma unroll
    for (int dt = 0; dt < 4; ++dt) o[dt] *= alpha;

    u32 pkv[4][2];
#pragma unroll
    for (int kt = 0; kt < 4; ++kt) {
      pkv[kt][0] = pk2(stl[kt][0], stl[kt][1]);
      pkv[kt][1] = pk2(stl[kt][2], stl[kt][3]);
    }
#pragma unroll
    for (int kh = 0; kh < 2; ++kh) {
      uint4 w4;
      u32* w4p = (u32*)&w4;
#pragma unroll
      for (int wd = 0; wd < 4; ++wd) {
        const int src = (2 * (hi & 1) + (wd >> 1)) * 16 + lo;
        const u32 a  = (u32)__shfl((int)pkv[2 * kh][wd & 1], src, 64);
        const u32 bb = (u32)__shfl((int)pkv[2 * kh + 1][wd & 1], src, 64);
        w4p[wd] = (hi < 2) ? a : bb;
      }
      const bf16x8 pf = __builtin_bit_cast(bf16x8, w4);
#pragma unroll
      for (int dt = 0; dt < 4; ++dt) {
        const bf16x8 vf = *(const bf16x8*)(smem + 8192 + (((dt * 2 + kh) * 64 + lane) << 4));
        o[dt] = MFMA16(vf, pf, o[dt]);
      }
    }
  }

  const float inv = gate[(size_t)qrow * H_ + h] / lrun;
  u16* yrow = y + (size_t)qrow * DIM_ + h * HD_;
#pragma unroll
  for (int dt = 0; dt < 4; ++dt) {
    ushort4 pq;
    pq.x = f2b(o[dt][0] * inv); pq.y = f2b(o[dt][1] * inv);
    pq.z = f2b(o[dt][2] * inv); pq.w = f2b(o[dt][3] * inv);
    *(ushort4*)(yrow + dt * 16 + hi * 4) = pq;
  }
}

// ---------------------------------------------------------------------------
extern "C" void kernel_launch(void* const* d_in, const int* in_sizes, int n_in,
                              void* d_out, int out_size, void* d_ws, size_t ws_size,
                              hipStream_t stream) {
  const float* x    = (const float*)d_in[0];
  const float* v1   = (const float*)d_in[1];
  const float* Wq   = (const float*)d_in[2];
  const float* Wk   = (const float*)d_in[3];
  const float* Wv   = (const float*)d_in[4];
  const float* Wp   = (const float*)d_in[5];
  const float* Wg   = (const float*)d_in[6];
  const float* lamb = (const float*)d_in[7];

  const size_t NX = (size_t)NROW * DIM_;        // 4M
  const size_t NW = (size_t)DIM_ * DIM_;        // 1M

  u16* q  = (u16*)d_ws;                         // also y (in-place)
  u16* k  = q + NX;
  u16* vt = k + NX;                             // [bh][d][t]
  u16* xb = vt + NX;
  u16* wb = xb + NX;                            // wqb|wkb|wvb|wpb (4M)
  float* gate = (float*)(wb + 4 * NW);          // total ws: 40.25 MB

  const dim3 bb(256);

  convert_all<<<dim3(8192), bb, 0, stream>>>(x, Wq, Wk, Wv, Wp, xb, wb);
  gemm97<false><<<dim3(NROW / 128, 24), bb, 0, stream>>>(
      xb, wb, q, k, vt, nullptr, v1, lamb);
  gate_kernel<<<dim3(NROW * H_ / 256), bb, 0, stream>>>(x, Wg, gate);
  attn3<<<dim3(B_ * H_ * (T_ / 64)), bb, 0, stream>>>(q, k, vt, gate, q);
  gemm97<true><<<dim3(NROW / 128, 8), bb, 0, stream>>>(
      q, wb + 3 * NW, nullptr, nullptr, nullptr, (float*)d_out, nullptr, nullptr);
}

// Round 8
// 237.079 us; speedup vs baseline: 8.7585x; 1.0556x over previous
//
#include <hip/hip_runtime.h>
#include <math.h>

// ---------------------------------------------------------------------------
// CausalSelfAttention fused pipeline, MI355X gfx950.  Round 8.
// r7: 250us. QKV gemm 99us @ MfmaUtil 9.8%, Occ 14.6% (2 blocks/CU, 2-barrier
// K-loop exposes full load latency at every barrier drain). This round:
// single-barrier DOUBLE-BUFFERED K-loop — stage tile i+1 right after the
// barrier publishing tile i, drain happens one compute-phase later. LDS 32KB.
// attn3 / gate / convert unchanged (r6/r7-verified).
// Workspace: q(=y) 8MB | k 8MB | vt 8MB | xb 8MB | w[4]b 8MB | gate 256KB.
// ---------------------------------------------------------------------------

#define B_    2
#define T_    2048
#define DIM_  1024
#define H_    16
#define HD_   64
#define NROW  (B_ * T_)
#define EPS_  1.1920929e-07f
#define SCALE_ 0.1f
#define LOG2_10K 13.287712379549449f

typedef unsigned short u16;
typedef unsigned int   u32;
typedef __bf16 bf16x8 __attribute__((ext_vector_type(8)));
typedef __bf16 bf16x2 __attribute__((ext_vector_type(2)));
typedef float  f32x4  __attribute__((ext_vector_type(4)));

__device__ __forceinline__ u16 f2b(float f) {
  u32 u = __float_as_uint(f);
  u += 0x7fffu + ((u >> 16) & 1u);       // RNE
  return (u16)(u >> 16);
}
__device__ __forceinline__ u32 pk2(float a, float b) {
#if __has_builtin(__builtin_amdgcn_cvt_pk_bf16_f32)
  bf16x2 r = __builtin_amdgcn_cvt_pk_bf16_f32(a, b);
  return __builtin_bit_cast(u32, r);
#else
  return (u32)f2b(a) | ((u32)f2b(b) << 16);
#endif
}
__device__ __forceinline__ void load16_lds(const u16* g, void* l) {
  __builtin_amdgcn_global_load_lds(
      (const __attribute__((address_space(1))) void*)g,
      (__attribute__((address_space(3))) void*)l, 16, 0, 0);
}
#define MFMA16(a,b,c) __builtin_amdgcn_mfma_f32_16x16x32_bf16((a),(b),(c),0,0,0)

// ---------------------------------------------------------------------------
// Convert pass: x (4M) and Wq/Wk/Wv/Wp (1M each) f32 -> bf16.
// ---------------------------------------------------------------------------
__global__ __launch_bounds__(256) void convert_all(
    const float* __restrict__ x, const float* __restrict__ Wq,
    const float* __restrict__ Wk, const float* __restrict__ Wv,
    const float* __restrict__ Wp,
    u16* __restrict__ xb, u16* __restrict__ wb /* wqb|wkb|wvb|wpb */) {
  const int i = blockIdx.x * 256 + threadIdx.x;       // 0 .. 2M-1 groups
  const float* src;
  u16* dst;
  int off;
  if (i < 1048576)       { src = x;  dst = xb;            off = i; }
  else if (i < 1310720)  { src = Wq; dst = wb;            off = i - 1048576; }
  else if (i < 1572864)  { src = Wk; dst = wb + 1048576;  off = i - 1310720; }
  else if (i < 1835008)  { src = Wv; dst = wb + 2097152;  off = i - 1572864; }
  else                   { src = Wp; dst = wb + 3145728;  off = i - 1835008; }
  const float4 f = ((const float4*)src)[off];
  uint2 o;
  o.x = pk2(f.x, f.y);
  o.y = pk2(f.z, f.w);
  ((uint2*)dst)[off] = o;
}

// ---------------------------------------------------------------------------
// Double-buffered m97-structure GEMM: C[row,n] = sum_k A[row,k]*W[n,k].
// 128x128 block tile, BK=32, 4 waves x (64x64 via 4x4 16x16x32 accs).
// LDS (32 KB): A buffers at {0, 8K}, B buffers at {16K, 24K}, fragment order
// (subtile s: 64 lanes x 16B at s*1024; lane slot = row s*16+(l&15),
//  k (l>>4)*8). K-loop: ONE barrier per iter; stage(i+1) issued right after
// the barrier that publishes tile i -> its vmcnt drain lands one
// compute-phase later (latency hidden even at 2 blocks/CU).
// IS_PROJ=false: grid (32,24), mode=by>>3: 0 q(rope) 1 k(rope) 2 v(blend,
//   transposed [bh][d][t] store); W = Wb + mode*1M.
// IS_PROJ=true: grid (32,8), W=Wb, f32 out.
// ---------------------------------------------------------------------------
template <bool IS_PROJ>
__global__ __launch_bounds__(256) void gemm_db(
    const u16* __restrict__ Ab, const u16* __restrict__ Wb,
    u16* __restrict__ qo, u16* __restrict__ ko, u16* __restrict__ vto,
    float* __restrict__ fo, const float* __restrict__ v1,
    const float* __restrict__ lambp) {
  __shared__ __attribute__((aligned(16))) unsigned char smem[32768];
  const int tid  = threadIdx.x;
  const int w    = tid >> 6;
  const int lane = tid & 63;
  const int lo = lane & 15, hi = lane >> 4;
  const int m0 = blockIdx.x << 7;
  const int by = blockIdx.y;
  const int mode = IS_PROJ ? 3 : (by >> 3);
  const int n0 = IS_PROJ ? (by << 7) : ((by & 7) << 7);
  const u16* W = IS_PROJ ? Wb : (Wb + (size_t)mode * (DIM_ * DIM_));

  const int wm = w & 1, wn = w >> 1;

  // staging pointers: wave w stages subtiles 2w, 2w+1 of A and B
  const u16* agA0 = Ab + (size_t)(m0 + (2 * w + 0) * 16 + lo) * DIM_ + (hi << 3);
  const u16* agA1 = Ab + (size_t)(m0 + (2 * w + 1) * 16 + lo) * DIM_ + (hi << 3);
  const u16* agB0 = W  + (size_t)(n0 + (2 * w + 0) * 16 + lo) * DIM_ + (hi << 3);
  const u16* agB1 = W  + (size_t)(n0 + (2 * w + 1) * 16 + lo) * DIM_ + (hi << 3);
  // wave-uniform LDS staging bases (per buffer ib: A at ib*8K, B at 16K+ib*8K)
  unsigned char* sA = smem + 2 * w * 1024;
  unsigned char* sB = smem + 16384 + 2 * w * 1024;

  f32x4 acc[4][4];
#pragma unroll
  for (int i = 0; i < 4; ++i)
#pragma unroll
    for (int j = 0; j < 4; ++j) acc[i][j] = (f32x4){0.f, 0.f, 0.f, 0.f};

  // prologue: stage tile 0 into buffer 0
  load16_lds(agA0, sA);
  load16_lds(agA1, sA + 1024);
  load16_lds(agB0, sB);
  load16_lds(agB1, sB + 1024);
  agA0 += 32; agA1 += 32; agB0 += 32; agB1 += 32;

  int ib = 0;
  for (int kc = 0; kc < DIM_; kc += 32, ib ^= 1) {
    __syncthreads();                 // tile(kc) in buf ib is published
    if (kc + 32 < DIM_) {            // stage tile(kc+32) into buf ib^1
      unsigned char* dA = sA + ((ib ^ 1) << 13);
      unsigned char* dB = sB + ((ib ^ 1) << 13);
      load16_lds(agA0, dA);
      load16_lds(agA1, dA + 1024);
      load16_lds(agB0, dB);
      load16_lds(agB1, dB + 1024);
      agA0 += 32; agA1 += 32; agB0 += 32; agB1 += 32;
    }
    const unsigned char* bufA = smem + (ib << 13);
    const unsigned char* bufB = smem + 16384 + (ib << 13);
    bf16x8 bfr[4];
#pragma unroll
    for (int nt = 0; nt < 4; ++nt)
      bfr[nt] = *(const bf16x8*)(bufB + (((wn * 4 + nt) * 64 + lane) << 4));
#pragma unroll
    for (int mt = 0; mt < 4; ++mt) {
      const bf16x8 af = *(const bf16x8*)(bufA + (((wm * 4 + mt) * 64 + lane) << 4));
#pragma unroll
      for (int nt = 0; nt < 4; ++nt)
        acc[mt][nt] = MFMA16(af, bfr[nt], acc[mt][nt]);
    }
  }

  // ---- register epilogues (r6/r7-verified) ----
  const int head = (n0 >> 6) + wn;
  if (mode <= 1) {
    u16* C = (mode == 0) ? qo : ko;
    const float if0 = exp2f(-(float)lo * (LOG2_10K / 32.f));
    const float if1 = exp2f(-(float)(lo + 16) * (LOG2_10K / 32.f));
#pragma unroll
    for (int mt = 0; mt < 4; ++mt)
#pragma unroll
      for (int r = 0; r < 4; ++r) {
        float ss = 0.f;
#pragma unroll
        for (int nt = 0; nt < 4; ++nt) { const float v = acc[mt][nt][r]; ss += v * v; }
        ss += __shfl_xor(ss, 1, 64); ss += __shfl_xor(ss, 2, 64);
        ss += __shfl_xor(ss, 4, 64); ss += __shfl_xor(ss, 8, 64);
        const float scl = rsqrtf(ss * (1.f / 64.f) + EPS_);
        const int row_g = m0 + wm * 64 + mt * 16 + hi * 4 + r;
        const float tpos = (float)(row_g & (T_ - 1));
        float sn0, cs0, sn1, cs1;
        sincosf(tpos * if0, &sn0, &cs0);
        sincosf(tpos * if1, &sn1, &cs1);
        u16* crow = C + (size_t)row_g * DIM_ + head * HD_;
        const float x10 = acc[mt][0][r] * scl, x11 = acc[mt][1][r] * scl;
        const float x20 = acc[mt][2][r] * scl, x21 = acc[mt][3][r] * scl;
        crow[lo]      = f2b(x10 * cs0 + x20 * sn0);
        crow[16 + lo] = f2b(x11 * cs1 + x21 * sn1);
        crow[32 + lo] = f2b(x20 * cs0 - x10 * sn0);
        crow[48 + lo] = f2b(x21 * cs1 - x11 * sn1);
      }
  } else if (mode == 2) {
    const float lam = lambp[0];
#pragma unroll
    for (int mt = 0; mt < 4; ++mt)
#pragma unroll
      for (int r = 0; r < 4; ++r) {
        const int row_g = m0 + wm * 64 + mt * 16 + hi * 4 + r;
        const int bb = row_g >> 11, tt = row_g & (T_ - 1);
        const int bh = bb * H_ + head;
        const float* v1r = v1 + (size_t)row_g * DIM_ + head * HD_;
#pragma unroll
        for (int nt = 0; nt < 4; ++nt) {
          const int d = nt * 16 + lo;
          const float ov = (1.f - lam) * acc[mt][nt][r] + lam * v1r[d];
          vto[((size_t)(bh * HD_ + d)) * T_ + tt] = f2b(ov);   // transposed
        }
      }
  } else {
#pragma unroll
    for (int mt = 0; mt < 4; ++mt)
#pragma unroll
      for (int r = 0; r < 4; ++r) {
        const int row_g = m0 + wm * 64 + mt * 16 + hi * 4 + r;
        float* orow = fo + (size_t)row_g * DIM_ + n0 + wn * 64;
#pragma unroll
        for (int nt = 0; nt < 4; ++nt) orow[nt * 16 + lo] = acc[mt][nt][r];
      }
  }
}

// ---------------------------------------------------------------------------
// gate[n,h] = sigmoid( sum_{j<12} x[n,j]*Wg[h,j] )
// ---------------------------------------------------------------------------
__global__ __launch_bounds__(256) void gate_kernel(
    const float* __restrict__ x, const float* __restrict__ Wg,
    float* __restrict__ gate) {
  const int id = blockIdx.x * 256 + threadIdx.x;
  const int n = id >> 4, h = id & 15;
  const float* xr = x + (size_t)n * DIM_;
  const float* wr = Wg + h * 12;
  float s = 0.f;
#pragma unroll
  for (int j = 0; j < 12; ++j) s += xr[j] * wr[j];
  gate[id] = 1.f / (1.f + __expf(-s));
}

// ---------------------------------------------------------------------------
// MFMA flash attention, S^T form (r6-verified). Block = (b,h,64-q tile).
// ---------------------------------------------------------------------------
__global__ __launch_bounds__(256) void attn3(
    const u16* __restrict__ q, const u16* __restrict__ k, const u16* __restrict__ vt,
    const float* __restrict__ gate, u16* __restrict__ y) {
  __shared__ __attribute__((aligned(16))) unsigned char smem[16384];
  const int tid = threadIdx.x;
  const int wv = tid >> 6, lane = tid & 63, lo = lane & 15, hi = lane >> 4;
  const int idx = blockIdx.x;
  const int qt = 31 - (idx >> 5);
  const int bh = idx & 31;
  const int b = bh >> 4, h = bh & 15;
  const int qb = qt << 6;

  const int qrow = b * T_ + qb + wv * 16 + lo;
  const u16* qp = q + (size_t)qrow * DIM_ + h * HD_;
  const bf16x8 qf0 = *(const bf16x8*)(qp + hi * 8);
  const bf16x8 qf1 = *(const bf16x8*)(qp + 32 + hi * 8);

  f32x4 o[4];
#pragma unroll
  for (int i = 0; i < 4; ++i) o[i] = (f32x4){0.f, 0.f, 0.f, 0.f};
  float mrun = -1e30f, lrun = 0.f;

  const int sl = tid & 63, skh = (tid >> 6) & 1, st0 = tid >> 7;
  const int srow = sl & 15, skk = skh * 32 + ((sl >> 4) << 3);
  const u16* kg0 = k + ((size_t)(b * T_ + st0 * 16 + srow)) * DIM_ + h * HD_ + skk;
  const u16* kg1 = kg0 + (size_t)32 * DIM_;
  const u16* vg0 = vt + ((size_t)(bh * HD_ + st0 * 16 + srow)) * T_ + skk;
  const u16* vg1 = vg0 + (size_t)32 * T_;

  uint4 kr0 = *(const uint4*)kg0, kr1 = *(const uint4*)kg1;
  uint4 vr0 = *(const uint4*)vg0, vr1 = *(const uint4*)vg1;

  const int off0 = tid << 4, off1 = (tid + 256) << 4;

  for (int tix = 0; tix <= qt; ++tix) {
    __syncthreads();
    *(uint4*)(smem + off0) = kr0;
    *(uint4*)(smem + off1) = kr1;
    *(uint4*)(smem + 8192 + off0) = vr0;
    *(uint4*)(smem + 8192 + off1) = vr1;
    if (tix < qt) {
      const size_t ko = (size_t)(tix + 1) * 64 * DIM_;
      const size_t vo = (size_t)(tix + 1) * 64;
      kr0 = *(const uint4*)(kg0 + ko); kr1 = *(const uint4*)(kg1 + ko);
      vr0 = *(const uint4*)(vg0 + vo); vr1 = *(const uint4*)(vg1 + vo);
    }
    __syncthreads();

    f32x4 stl[4];
#pragma unroll
    for (int kt = 0; kt < 4; ++kt) stl[kt] = (f32x4){0.f, 0.f, 0.f, 0.f};
#pragma unroll
    for (int kh = 0; kh < 2; ++kh) {
      const bf16x8 qb_ = kh ? qf1 : qf0;
#pragma unroll
      for (int kt = 0; kt < 4; ++kt) {
        const bf16x8 af = *(const bf16x8*)(smem + (((kt * 2 + kh) * 64 + lane) << 4));
        stl[kt] = MFMA16(af, qb_, stl[kt]);
      }
    }
    const bool diag = (tix == qt);
#pragma unroll
    for (int kt = 0; kt < 4; ++kt)
#pragma unroll
      for (int r = 0; r < 4; ++r) {
        float s = stl[kt][r] * SCALE_;
        if (diag && (kt * 16 + hi * 4 + r > wv * 16 + lo)) s = -3e38f;
        stl[kt][r] = s;
      }
    float mx = stl[0][0];
#pragma unroll
    for (int kt = 0; kt < 4; ++kt)
#pragma unroll
      for (int r = 0; r < 4; ++r) mx = fmaxf(mx, stl[kt][r]);
    mx = fmaxf(mx, __shfl_xor(mx, 16, 64));
    mx = fmaxf(mx, __shfl_xor(mx, 32, 64));
    const float mn = fmaxf(mrun, mx);
    const float alpha = __expf(mrun - mn);
    mrun = mn;
    float ps = 0.f;
#pragma unroll
    for (int kt = 0; kt < 4; ++kt)
#pragma unroll
      for (int r = 0; r < 4; ++r) { stl[kt][r] = __expf(stl[kt][r] - mn); ps += stl[kt][r]; }
    ps += __shfl_xor(ps, 16, 64);
    ps += __shfl_xor(ps, 32, 64);
    lrun = lrun * alpha + ps;
#pragma unroll
    for (int dt = 0; dt < 4; ++dt) o[dt] *= alpha;

    u32 pkv[4][2];
#pragma unroll
    for (int kt = 0; kt < 4; ++kt) {
      pkv[kt][0] = pk2(stl[kt][0], stl[kt][1]);
      pkv[kt][1] = pk2(stl[kt][2], stl[kt][3]);
    }
#pragma unroll
    for (int kh = 0; kh < 2; ++kh) {
      uint4 w4;
      u32* w4p = (u32*)&w4;
#pragma unroll
      for (int wd = 0; wd < 4; ++wd) {
        const int src = (2 * (hi & 1) + (wd >> 1)) * 16 + lo;
        const u32 a  = (u32)__shfl((int)pkv[2 * kh][wd & 1], src, 64);
        const u32 bb = (u32)__shfl((int)pkv[2 * kh + 1][wd & 1], src, 64);
        w4p[wd] = (hi < 2) ? a : bb;
      }
      const bf16x8 pf = __builtin_bit_cast(bf16x8, w4);
#pragma unroll
      for (int dt = 0; dt < 4; ++dt) {
        const bf16x8 vf = *(const bf16x8*)(smem + 8192 + (((dt * 2 + kh) * 64 + lane) << 4));
        o[dt] = MFMA16(vf, pf, o[dt]);
      }
    }
  }

  const float inv = gate[(size_t)qrow * H_ + h] / lrun;
  u16* yrow = y + (size_t)qrow * DIM_ + h * HD_;
#pragma unroll
  for (int dt = 0; dt < 4; ++dt) {
    ushort4 pq;
    pq.x = f2b(o[dt][0] * inv); pq.y = f2b(o[dt][1] * inv);
    pq.z = f2b(o[dt][2] * inv); pq.w = f2b(o[dt][3] * inv);
    *(ushort4*)(yrow + dt * 16 + hi * 4) = pq;
  }
}

// ---------------------------------------------------------------------------
extern "C" void kernel_launch(void* const* d_in, const int* in_sizes, int n_in,
                              void* d_out, int out_size, void* d_ws, size_t ws_size,
                              hipStream_t stream) {
  const float* x    = (const float*)d_in[0];
  const float* v1   = (const float*)d_in[1];
  const float* Wq   = (const float*)d_in[2];
  const float* Wk   = (const float*)d_in[3];
  const float* Wv   = (const float*)d_in[4];
  const float* Wp   = (const float*)d_in[5];
  const float* Wg   = (const float*)d_in[6];
  const float* lamb = (const float*)d_in[7];

  const size_t NX = (size_t)NROW * DIM_;        // 4M
  const size_t NW = (size_t)DIM_ * DIM_;        // 1M

  u16* q  = (u16*)d_ws;                         // also y (in-place)
  u16* k  = q + NX;
  u16* vt = k + NX;                             // [bh][d][t]
  u16* xb = vt + NX;
  u16* wb = xb + NX;                            // wqb|wkb|wvb|wpb (4M)
  float* gate = (float*)(wb + 4 * NW);          // total ws: 40.25 MB

  const dim3 bb(256);

  convert_all<<<dim3(8192), bb, 0, stream>>>(x, Wq, Wk, Wv, Wp, xb, wb);
  gemm_db<false><<<dim3(NROW / 128, 24), bb, 0, stream>>>(
      xb, wb, q, k, vt, nullptr, v1, lamb);
  gate_kernel<<<dim3(NROW * H_ / 256), bb, 0, stream>>>(x, Wg, gate);
  attn3<<<dim3(B_ * H_ * (T_ / 64)), bb, 0, stream>>>(q, k, vt, gate, q);
  gemm_db<true><<<dim3(NROW / 128, 8), bb, 0, stream>>>(
      q, wb + 3 * NW, nullptr, nullptr, nullptr, (float*)d_out, nullptr, nullptr);
}